// Round 7
// baseline (803.381 us; speedup 1.0000x reference)
//
#include <hip/hip_runtime.h>
#include <stdint.h>

// ---------- types ----------
typedef __attribute__((ext_vector_type(8))) __bf16 bf16x8;
typedef __attribute__((ext_vector_type(4))) float f32x4;

#define MIN_WF 0.001f
#define MIN_HF 0.001f
#define MIN_DF 0.001f
#define BN_INV 0.99999500003749977f /* 1/sqrt(1+1e-5) */

// async global->LDS, 16B per lane; LDS dest = wave-uniform base + lane*16
#define GLL(g, l)                                                              \
  __builtin_amdgcn_global_load_lds(                                            \
      (const __attribute__((address_space(1))) void*)(g),                      \
      (__attribute__((address_space(3))) void*)(l), 16, 0, 0)

__device__ __forceinline__ unsigned short f2bf(float f) {
  union { float f; unsigned int u; } v; v.f = f;
  unsigned int r = v.u + 0x7FFFu + ((v.u >> 16) & 1u);
  return (unsigned short)(r >> 16);
}

// ---------- cast/select even columns of x -> bf16 (Bc x 64) ----------
__global__ void cast_x_kernel(const float* __restrict__ x, unsigned short* __restrict__ xt) {
  int gid = blockIdx.x * blockDim.x + threadIdx.x; // 0 .. Bc*64
  int b = gid >> 6, i = gid & 63;
  xt[gid] = f2bf(x[(size_t)b * 128 + 2 * i]);
}

// ---------- transpose + cast: W (KxN f32, row-major) -> Wt (NxK bf16) ----------
__global__ void transpose_cast_kernel(const float* __restrict__ W, unsigned short* __restrict__ Wt,
                                      int K, int N) {
  __shared__ float tile[32][33];
  int tx = threadIdx.x & 31, ty = threadIdx.x >> 5; // 256 threads: ty 0..7
  int n0 = blockIdx.x * 32, k0 = blockIdx.y * 32;
#pragma unroll
  for (int i = 0; i < 32; i += 8)
    tile[ty + i][tx] = W[(size_t)(k0 + ty + i) * N + n0 + tx];
  __syncthreads();
#pragma unroll
  for (int i = 0; i < 32; i += 8)
    Wt[(size_t)(n0 + ty + i) * K + k0 + tx] = f2bf(tile[tx][ty + i]);
}

// ---------- GEMM: C[M,N] = epi(A[M,K] @ Bt[N,K]^T) ----------
// m97 staging, K=64/barrier via two BK=32 planes, XOR-swizzled LDS banks.
// Swizzle: physical 16B-group p = (logical g + ((row>>1)&3)) & 3. DMA layout
// stays contiguous; the *global source* group per staging lane is rotated.
// EPI==1: v=relu(v+bias); v=gamma*BN_INV*v+beta; store bf16.  EPI==0: v=v+bias; store f32.
template <int EPI>
__global__ __launch_bounds__(256) void gemm_bt_kernel(
    const unsigned short* __restrict__ A, const unsigned short* __restrict__ Bt,
    const float* __restrict__ bias, const float* __restrict__ gamma,
    const float* __restrict__ beta, void* __restrict__ Cout,
    int M, int N, int K) {
  constexpr int BM = 128, BN = 128, BK = 32;
  __shared__ __align__(16) unsigned short As[2][BM * BK]; // 16 KB
  __shared__ __align__(16) unsigned short Bs[2][BN * BK]; // 16 KB
  int tid = threadIdx.x;
  int lane = tid & 63;
  int wave = tid >> 6;
  int wm = (wave & 1) * 64;
  int wn = (wave >> 1) * 64;
  int ml = lane & 15;
  int kq = lane >> 4;
  size_t bm = (size_t)blockIdx.x * BM;
  size_t bn = (size_t)blockIdx.y * BN;

  // staging: wave w stages rows [w*32, +32); lane covers row sr=lane>>2.
  // physical group cg=lane&3 holds logical group g=(cg - (sr>>1))&3.
  int sr = lane >> 2;
  int sc = ((((lane & 3) + 4) - ((lane >> 3) & 3)) & 3) * 8;
  const unsigned short* gA = A + (bm + wave * 32 + sr) * (size_t)K + sc;
  const unsigned short* gB = Bt + (bn + wave * 32 + sr) * (size_t)K + sc;
  unsigned short* lA0 = As[0] + wave * 32 * BK;
  unsigned short* lA1 = As[1] + wave * 32 * BK;
  unsigned short* lB0 = Bs[0] + wave * 32 * BK;
  unsigned short* lB1 = Bs[1] + wave * 32 * BK;

  // fragment-read swizzle: rows are wm+i*16+ml / wn+j*16+ml, so (row>>1)&3
  // == (ml>>1)&3 for all i/j -> one precomputed physical group per thread.
  int kqs = ((kq + ((ml >> 1) & 3)) & 3) * 8;

  f32x4 zero = {0.f, 0.f, 0.f, 0.f};
  f32x4 acc[4][4];
#pragma unroll
  for (int i = 0; i < 4; i++)
#pragma unroll
    for (int j = 0; j < 4; j++) acc[i][j] = zero;

  for (int kb = 0; kb < K; kb += 64) {
    GLL(gA + kb, lA0);
    GLL(gA + kb + (size_t)16 * K, lA0 + 16 * BK);
    GLL(gA + kb + 32, lA1);
    GLL(gA + kb + 32 + (size_t)16 * K, lA1 + 16 * BK);
    GLL(gB + kb, lB0);
    GLL(gB + kb + (size_t)16 * K, lB0 + 16 * BK);
    GLL(gB + kb + 32, lB1);
    GLL(gB + kb + 32 + (size_t)16 * K, lB1 + 16 * BK);
    __syncthreads(); // vmcnt(0) drain: LDS-DMA complete

#pragma unroll
    for (int p = 0; p < 2; p++) {
      bf16x8 af[4], bfr[4];
#pragma unroll
      for (int i = 0; i < 4; i++)
        af[i] = *(const bf16x8*)(&As[p][(wm + i * 16 + ml) * BK + kqs]);
#pragma unroll
      for (int j = 0; j < 4; j++)
        bfr[j] = *(const bf16x8*)(&Bs[p][(wn + j * 16 + ml) * BK + kqs]);
#pragma unroll
      for (int i = 0; i < 4; i++)
#pragma unroll
        for (int j = 0; j < 4; j++)
          acc[i][j] = __builtin_amdgcn_mfma_f32_16x16x32_bf16(af[i], bfr[j], acc[i][j], 0, 0, 0);
    }
    __syncthreads();
  }

  // epilogue. D mapping: col = lane&15, row = (lane>>4)*4 + r
#pragma unroll
  for (int i = 0; i < 4; i++) {
#pragma unroll
    for (int j = 0; j < 4; j++) {
      size_t col = bn + wn + j * 16 + ml;
      float bv = bias[col];
      float gv = (EPI == 1) ? gamma[col] * BN_INV : 0.f;
      float bev = (EPI == 1) ? beta[col] : 0.f;
#pragma unroll
      for (int r = 0; r < 4; r++) {
        size_t row = bm + wm + i * 16 + kq * 4 + r;
        float v = acc[i][j][r] + bv;
        if (EPI == 1) {
          v = fmaxf(v, 0.f);
          v = gv * v + bev;
          ((unsigned short*)Cout)[row * (size_t)N + col] = f2bf(v);
        } else {
          ((float*)Cout)[row * (size_t)N + col] = v;
        }
      }
    }
  }
}

// ---------- RQ spline + output assembly + log_det ----------
__global__ void spline_kernel(const float* __restrict__ x, const float* __restrict__ params,
                              float* __restrict__ out, float* __restrict__ logdet) {
  int gid = blockIdx.x * blockDim.x + threadIdx.x; // 0 .. Bc*64
  int b = gid >> 6;
  int i = gid & 63;

  const float4* p = (const float4*)(params + (size_t)gid * 24);
  float4 q0 = p[0], q1 = p[1], q2 = p[2], q3 = p[3], q4 = p[4], q5 = p[5];
  float w[8] = {q0.x, q0.y, q0.z, q0.w, q1.x, q1.y, q1.z, q1.w};
  float hh[8] = {q2.x, q2.y, q2.z, q2.w, q3.x, q3.y, q3.z, q3.w};
  float dv[8] = {q4.x, q4.y, q4.z, q4.w, q5.x, q5.y, q5.z, q5.w};

  float mx = w[0];
#pragma unroll
  for (int k = 1; k < 8; k++) mx = fmaxf(mx, w[k]);
  float s = 0.f;
#pragma unroll
  for (int k = 0; k < 8; k++) { w[k] = expf(w[k] - mx); s += w[k]; }
  float sc = (1.f - 8.f * MIN_WF) / s;
  float cw[9];
  cw[0] = 0.f;
#pragma unroll
  for (int k = 0; k < 8; k++) cw[k + 1] = cw[k] + (MIN_WF + sc * w[k]);

  float mh = hh[0];
#pragma unroll
  for (int k = 1; k < 8; k++) mh = fmaxf(mh, hh[k]);
  float sh = 0.f;
#pragma unroll
  for (int k = 0; k < 8; k++) { hh[k] = expf(hh[k] - mh); sh += hh[k]; }
  float sch = (1.f - 8.f * MIN_HF) / sh;
  float ch[9];
  ch[0] = 0.f;
#pragma unroll
  for (int k = 0; k < 8; k++) ch[k + 1] = ch[k] + (MIN_HF + sch * hh[k]);

  float dk[9];
#pragma unroll
  for (int k = 0; k < 8; k++)
    dk[k] = MIN_DF + (fmaxf(dv[k], 0.f) + log1pf(expf(-fabsf(dv[k]))));
  dk[8] = MIN_DF;

  float xv = x[(size_t)b * 128 + 2 * i + 1]; // identity (odd) column

  int bi = 0;
#pragma unroll
  for (int k = 0; k < 8; k++) bi += (xv > cw[k]) ? 1 : 0;
  bi = (bi > 7) ? 7 : bi;

  float xl = 0.f, xr = 0.f, yl = 0.f, yr = 0.f, dl = 0.f, dr = 0.f;
#pragma unroll
  for (int k = 0; k < 8; k++) {
    if (k == bi) {
      xl = cw[k]; xr = cw[k + 1];
      yl = ch[k]; yr = ch[k + 1];
      dl = dk[k]; dr = dk[k + 1];
    }
  }

  float bw = xr - xl, bh = yr - yl;
  float t = (xv - xl) / bw;
  t = fminf(fmaxf(t, 0.f), 1.f);
  float num = bh * (dl * t * t + 2.f * t * (1.f - t));
  float den = dl + (dr - dl) * t;
  float o = yl + num / den;
  float ld = logf(bh) + 2.f * logf(2.f * t * (1.f - t) * dr + dl) - logf(den);

  float xe = x[(size_t)b * 128 + 2 * i]; // transform (even) column passthrough
  ((float2*)out)[(size_t)b * 64 + i] = make_float2(xe, o);

#pragma unroll
  for (int off = 32; off > 0; off >>= 1) ld += __shfl_xor(ld, off, 64);
  if ((threadIdx.x & 63) == 0) logdet[b] = ld;
}

// ---------- launch ----------
extern "C" void kernel_launch(void* const* d_in, const int* in_sizes, int n_in,
                              void* d_out, int out_size, void* d_ws, size_t ws_size,
                              hipStream_t stream) {
  const float* x   = (const float*)d_in[0];
  const float* W1  = (const float*)d_in[1];
  const float* b1  = (const float*)d_in[2];
  const float* g1  = (const float*)d_in[3];
  const float* be1 = (const float*)d_in[4];
  const float* W2  = (const float*)d_in[5];
  const float* b2  = (const float*)d_in[6];
  const float* g2  = (const float*)d_in[7];
  const float* be2 = (const float*)d_in[8];
  const float* W3  = (const float*)d_in[9];
  const float* b3  = (const float*)d_in[10];

  const int B = 32768, H = 2048, DOUT = 1536;

  // ---- workspace layout (chunked) ----
  // persistent weights: W1t 262,144 + W2t 8,388,608 + W3t 6,291,456 = 14,942,208 B
  // per chunk of Bc rows: xt 128*Bc + h2 4096*Bc + max(h1 4096*Bc, params 6144*Bc)
  const size_t WEIGHTS = 14942208;
  int Bc = 1024;
  {
    const int cand[5] = {32768, 16384, 8192, 4096, 2048};
    for (int c = 0; c < 5; c++) {
      size_t need = WEIGHTS + (size_t)10368 * cand[c];
      if (need <= ws_size) { Bc = cand[c]; break; }
    }
  }
  char* ws = (char*)d_ws;
  unsigned short* W1t = (unsigned short*)(ws + 0);
  unsigned short* W2t = (unsigned short*)(ws + 262144);
  unsigned short* W3t = (unsigned short*)(ws + 8650752);
  unsigned short* xt  = (unsigned short*)(ws + WEIGHTS);
  unsigned short* h2  = (unsigned short*)(ws + WEIGHTS + (size_t)128 * Bc);
  char*           uni = ws + WEIGHTS + (size_t)(128 + 4096) * Bc;
  unsigned short* h1  = (unsigned short*)uni;
  float*      params  = (float*)uni; // aliases h1 (dead when GEMM3 writes)

  float* out = (float*)d_out;
  float* logdet = out + (size_t)B * 128;

  transpose_cast_kernel<<<dim3(64, 2), dim3(256), 0, stream>>>(W1, W1t, 64, H);
  transpose_cast_kernel<<<dim3(64, 64), dim3(256), 0, stream>>>(W2, W2t, H, H);
  transpose_cast_kernel<<<dim3(48, 64), dim3(256), 0, stream>>>(W3, W3t, H, DOUT);

  for (int r0 = 0; r0 < B; r0 += Bc) {
    cast_x_kernel<<<dim3(Bc / 4), dim3(256), 0, stream>>>(x + (size_t)r0 * 128, xt);
    gemm_bt_kernel<1><<<dim3(Bc / 128, 16), dim3(256), 0, stream>>>(
        xt, W1t, b1, g1, be1, (void*)h1, Bc, H, 64);
    gemm_bt_kernel<1><<<dim3(Bc / 128, 16), dim3(256), 0, stream>>>(
        h1, W2t, b2, g2, be2, (void*)h2, Bc, H, H);
    gemm_bt_kernel<0><<<dim3(Bc / 128, 12), dim3(256), 0, stream>>>(
        h2, W3t, b3, b3, b3, (void*)params, Bc, DOUT, H);
    spline_kernel<<<dim3(Bc / 4), dim3(256), 0, stream>>>(
        x + (size_t)r0 * 128, params, out + (size_t)r0 * 128, logdet + r0);
  }
}

// Round 8
// 799.825 us; speedup vs baseline: 1.0044x; 1.0044x over previous
//
#include <hip/hip_runtime.h>
#include <stdint.h>

// ---------- types ----------
typedef __attribute__((ext_vector_type(8))) __bf16 bf16x8;
typedef __attribute__((ext_vector_type(4))) float f32x4;

#define MIN_WF 0.001f
#define MIN_HF 0.001f
#define MIN_DF 0.001f
#define BN_INV 0.99999500003749977f /* 1/sqrt(1+1e-5) */

// async global->LDS, 16B per lane; LDS dest = wave-uniform base + lane*16
#define GLL(g, l)                                                              \
  __builtin_amdgcn_global_load_lds(                                            \
      (const __attribute__((address_space(1))) void*)(g),                      \
      (__attribute__((address_space(3))) void*)(l), 16, 0, 0)

__device__ __forceinline__ unsigned short f2bf(float f) {
  union { float f; unsigned int u; } v; v.f = f;
  unsigned int r = v.u + 0x7FFFu + ((v.u >> 16) & 1u);
  return (unsigned short)(r >> 16);
}

// ---------- cast/select even columns of x -> bf16 (Bc x 64) ----------
__global__ void cast_x_kernel(const float* __restrict__ x, unsigned short* __restrict__ xt) {
  int gid = blockIdx.x * blockDim.x + threadIdx.x; // 0 .. Bc*64
  int b = gid >> 6, i = gid & 63;
  xt[gid] = f2bf(x[(size_t)b * 128 + 2 * i]);
}

// ---------- transpose + cast: W (KxN f32, row-major) -> Wt (NxK bf16) ----------
__global__ void transpose_cast_kernel(const float* __restrict__ W, unsigned short* __restrict__ Wt,
                                      int K, int N) {
  __shared__ float tile[32][33];
  int tx = threadIdx.x & 31, ty = threadIdx.x >> 5; // 256 threads: ty 0..7
  int n0 = blockIdx.x * 32, k0 = blockIdx.y * 32;
#pragma unroll
  for (int i = 0; i < 32; i += 8)
    tile[ty + i][tx] = W[(size_t)(k0 + ty + i) * N + n0 + tx];
  __syncthreads();
#pragma unroll
  for (int i = 0; i < 32; i += 8)
    Wt[(size_t)(n0 + ty + i) * K + k0 + tx] = f2bf(tile[tx][ty + i]);
}

// ---------- GEMM: C[M,N] = epi(A[M,K] @ Bt[N,K]^T) ----------
// m97 staging, K=64/barrier via two BK=32 planes, XOR-swizzled LDS banks.
// Grid order: blockIdx.x = N-tile (fastest), blockIdx.y = M-tile, so the
// blocks sharing one A M-strip are consecutive in dispatch order ->
// co-resident -> A-strip staged from XCD-L2 instead of HBM after first touch.
// EPI==1: v=relu(v+bias); v=gamma*BN_INV*v+beta; store bf16.  EPI==0: v=v+bias; store f32.
template <int EPI>
__global__ __launch_bounds__(256) void gemm_bt_kernel(
    const unsigned short* __restrict__ A, const unsigned short* __restrict__ Bt,
    const float* __restrict__ bias, const float* __restrict__ gamma,
    const float* __restrict__ beta, void* __restrict__ Cout,
    int M, int N, int K) {
  constexpr int BM = 128, BN = 128, BK = 32;
  __shared__ __align__(16) unsigned short As[2][BM * BK]; // 16 KB
  __shared__ __align__(16) unsigned short Bs[2][BN * BK]; // 16 KB
  int tid = threadIdx.x;
  int lane = tid & 63;
  int wave = tid >> 6;
  int wm = (wave & 1) * 64;
  int wn = (wave >> 1) * 64;
  int ml = lane & 15;
  int kq = lane >> 4;
  size_t bm = (size_t)blockIdx.y * BM; // M-tile: slow grid axis
  size_t bn = (size_t)blockIdx.x * BN; // N-tile: fast grid axis

  // staging: wave w stages rows [w*32, +32); lane covers row sr=lane>>2.
  // physical group cg=lane&3 holds logical group g=(cg - (sr>>1))&3.
  int sr = lane >> 2;
  int sc = ((((lane & 3) + 4) - ((lane >> 3) & 3)) & 3) * 8;
  const unsigned short* gA = A + (bm + wave * 32 + sr) * (size_t)K + sc;
  const unsigned short* gB = Bt + (bn + wave * 32 + sr) * (size_t)K + sc;
  unsigned short* lA0 = As[0] + wave * 32 * BK;
  unsigned short* lA1 = As[1] + wave * 32 * BK;
  unsigned short* lB0 = Bs[0] + wave * 32 * BK;
  unsigned short* lB1 = Bs[1] + wave * 32 * BK;

  // fragment-read swizzle: physical group p = (kq + ((ml>>1)&3)) & 3 (i/j-invariant).
  int kqs = ((kq + ((ml >> 1) & 3)) & 3) * 8;

  f32x4 zero = {0.f, 0.f, 0.f, 0.f};
  f32x4 acc[4][4];
#pragma unroll
  for (int i = 0; i < 4; i++)
#pragma unroll
    for (int j = 0; j < 4; j++) acc[i][j] = zero;

  for (int kb = 0; kb < K; kb += 64) {
    GLL(gA + kb, lA0);
    GLL(gA + kb + (size_t)16 * K, lA0 + 16 * BK);
    GLL(gA + kb + 32, lA1);
    GLL(gA + kb + 32 + (size_t)16 * K, lA1 + 16 * BK);
    GLL(gB + kb, lB0);
    GLL(gB + kb + (size_t)16 * K, lB0 + 16 * BK);
    GLL(gB + kb + 32, lB1);
    GLL(gB + kb + 32 + (size_t)16 * K, lB1 + 16 * BK);
    __syncthreads(); // vmcnt(0) drain: LDS-DMA complete

#pragma unroll
    for (int p = 0; p < 2; p++) {
      bf16x8 af[4], bfr[4];
#pragma unroll
      for (int i = 0; i < 4; i++)
        af[i] = *(const bf16x8*)(&As[p][(wm + i * 16 + ml) * BK + kqs]);
#pragma unroll
      for (int j = 0; j < 4; j++)
        bfr[j] = *(const bf16x8*)(&Bs[p][(wn + j * 16 + ml) * BK + kqs]);
#pragma unroll
      for (int i = 0; i < 4; i++)
#pragma unroll
        for (int j = 0; j < 4; j++)
          acc[i][j] = __builtin_amdgcn_mfma_f32_16x16x32_bf16(af[i], bfr[j], acc[i][j], 0, 0, 0);
    }
    __syncthreads();
  }

  // epilogue. D mapping: col = lane&15, row = (lane>>4)*4 + r
#pragma unroll
  for (int i = 0; i < 4; i++) {
#pragma unroll
    for (int j = 0; j < 4; j++) {
      size_t col = bn + wn + j * 16 + ml;
      float bv = bias[col];
      float gv = (EPI == 1) ? gamma[col] * BN_INV : 0.f;
      float bev = (EPI == 1) ? beta[col] : 0.f;
#pragma unroll
      for (int r = 0; r < 4; r++) {
        size_t row = bm + wm + i * 16 + kq * 4 + r;
        float v = acc[i][j][r] + bv;
        if (EPI == 1) {
          v = fmaxf(v, 0.f);
          v = gv * v + bev;
          ((unsigned short*)Cout)[row * (size_t)N + col] = f2bf(v);
        } else {
          ((float*)Cout)[row * (size_t)N + col] = v;
        }
      }
    }
  }
}

// ---------- RQ spline + output assembly + log_det ----------
__global__ void spline_kernel(const float* __restrict__ x, const float* __restrict__ params,
                              float* __restrict__ out, float* __restrict__ logdet) {
  int gid = blockIdx.x * blockDim.x + threadIdx.x; // 0 .. Bc*64
  int b = gid >> 6;
  int i = gid & 63;

  const float4* p = (const float4*)(params + (size_t)gid * 24);
  float4 q0 = p[0], q1 = p[1], q2 = p[2], q3 = p[3], q4 = p[4], q5 = p[5];
  float w[8] = {q0.x, q0.y, q0.z, q0.w, q1.x, q1.y, q1.z, q1.w};
  float hh[8] = {q2.x, q2.y, q2.z, q2.w, q3.x, q3.y, q3.z, q3.w};
  float dv[8] = {q4.x, q4.y, q4.z, q4.w, q5.x, q5.y, q5.z, q5.w};

  float mx = w[0];
#pragma unroll
  for (int k = 1; k < 8; k++) mx = fmaxf(mx, w[k]);
  float s = 0.f;
#pragma unroll
  for (int k = 0; k < 8; k++) { w[k] = expf(w[k] - mx); s += w[k]; }
  float sc = (1.f - 8.f * MIN_WF) / s;
  float cw[9];
  cw[0] = 0.f;
#pragma unroll
  for (int k = 0; k < 8; k++) cw[k + 1] = cw[k] + (MIN_WF + sc * w[k]);

  float mh = hh[0];
#pragma unroll
  for (int k = 1; k < 8; k++) mh = fmaxf(mh, hh[k]);
  float sh = 0.f;
#pragma unroll
  for (int k = 0; k < 8; k++) { hh[k] = expf(hh[k] - mh); sh += hh[k]; }
  float sch = (1.f - 8.f * MIN_HF) / sh;
  float ch[9];
  ch[0] = 0.f;
#pragma unroll
  for (int k = 0; k < 8; k++) ch[k + 1] = ch[k] + (MIN_HF + sch * hh[k]);

  float dk[9];
#pragma unroll
  for (int k = 0; k < 8; k++)
    dk[k] = MIN_DF + (fmaxf(dv[k], 0.f) + log1pf(expf(-fabsf(dv[k]))));
  dk[8] = MIN_DF;

  float xv = x[(size_t)b * 128 + 2 * i + 1]; // identity (odd) column

  int bi = 0;
#pragma unroll
  for (int k = 0; k < 8; k++) bi += (xv > cw[k]) ? 1 : 0;
  bi = (bi > 7) ? 7 : bi;

  float xl = 0.f, xr = 0.f, yl = 0.f, yr = 0.f, dl = 0.f, dr = 0.f;
#pragma unroll
  for (int k = 0; k < 8; k++) {
    if (k == bi) {
      xl = cw[k]; xr = cw[k + 1];
      yl = ch[k]; yr = ch[k + 1];
      dl = dk[k]; dr = dk[k + 1];
    }
  }

  float bw = xr - xl, bh = yr - yl;
  float t = (xv - xl) / bw;
  t = fminf(fmaxf(t, 0.f), 1.f);
  float num = bh * (dl * t * t + 2.f * t * (1.f - t));
  float den = dl + (dr - dl) * t;
  float o = yl + num / den;
  float ld = logf(bh) + 2.f * logf(2.f * t * (1.f - t) * dr + dl) - logf(den);

  float xe = x[(size_t)b * 128 + 2 * i]; // transform (even) column passthrough
  ((float2*)out)[(size_t)b * 64 + i] = make_float2(xe, o);

#pragma unroll
  for (int off = 32; off > 0; off >>= 1) ld += __shfl_xor(ld, off, 64);
  if ((threadIdx.x & 63) == 0) logdet[b] = ld;
}

// ---------- launch ----------
extern "C" void kernel_launch(void* const* d_in, const int* in_sizes, int n_in,
                              void* d_out, int out_size, void* d_ws, size_t ws_size,
                              hipStream_t stream) {
  const float* x   = (const float*)d_in[0];
  const float* W1  = (const float*)d_in[1];
  const float* b1  = (const float*)d_in[2];
  const float* g1  = (const float*)d_in[3];
  const float* be1 = (const float*)d_in[4];
  const float* W2  = (const float*)d_in[5];
  const float* b2  = (const float*)d_in[6];
  const float* g2  = (const float*)d_in[7];
  const float* be2 = (const float*)d_in[8];
  const float* W3  = (const float*)d_in[9];
  const float* b3  = (const float*)d_in[10];

  const int B = 32768, H = 2048, DOUT = 1536;

  // ---- workspace layout (chunked) ----
  // persistent weights: W1t 262,144 + W2t 8,388,608 + W3t 6,291,456 = 14,942,208 B
  // per chunk of Bc rows: xt 128*Bc + h2 4096*Bc + max(h1 4096*Bc, params 6144*Bc)
  const size_t WEIGHTS = 14942208;
  int Bc = 1024;
  {
    const int cand[5] = {32768, 16384, 8192, 4096, 2048};
    for (int c = 0; c < 5; c++) {
      size_t need = WEIGHTS + (size_t)10368 * cand[c];
      if (need <= ws_size) { Bc = cand[c]; break; }
    }
  }
  char* ws = (char*)d_ws;
  unsigned short* W1t = (unsigned short*)(ws + 0);
  unsigned short* W2t = (unsigned short*)(ws + 262144);
  unsigned short* W3t = (unsigned short*)(ws + 8650752);
  unsigned short* xt  = (unsigned short*)(ws + WEIGHTS);
  unsigned short* h2  = (unsigned short*)(ws + WEIGHTS + (size_t)128 * Bc);
  char*           uni = ws + WEIGHTS + (size_t)(128 + 4096) * Bc;
  unsigned short* h1  = (unsigned short*)uni;
  float*      params  = (float*)uni; // aliases h1 (dead when GEMM3 writes)

  float* out = (float*)d_out;
  float* logdet = out + (size_t)B * 128;

  transpose_cast_kernel<<<dim3(64, 2), dim3(256), 0, stream>>>(W1, W1t, 64, H);
  transpose_cast_kernel<<<dim3(64, 64), dim3(256), 0, stream>>>(W2, W2t, H, H);
  transpose_cast_kernel<<<dim3(48, 64), dim3(256), 0, stream>>>(W3, W3t, H, DOUT);

  // NOTE: grid = (Ntiles, Mtiles) — N-tile fastest; kernel reads
  // bm from blockIdx.y, bn from blockIdx.x.
  for (int r0 = 0; r0 < B; r0 += Bc) {
    cast_x_kernel<<<dim3(Bc / 4), dim3(256), 0, stream>>>(x + (size_t)r0 * 128, xt);
    gemm_bt_kernel<1><<<dim3(16, Bc / 128), dim3(256), 0, stream>>>(
        xt, W1t, b1, g1, be1, (void*)h1, Bc, H, 64);
    gemm_bt_kernel<1><<<dim3(16, Bc / 128), dim3(256), 0, stream>>>(
        h1, W2t, b2, g2, be2, (void*)h2, Bc, H, H);
    gemm_bt_kernel<0><<<dim3(12, Bc / 128), dim3(256), 0, stream>>>(
        h2, W3t, b3, b3, b3, (void*)params, Bc, DOUT, H);
    spline_kernel<<<dim3(Bc / 4), dim3(256), 0, stream>>>(
        x + (size_t)r0 * 128, params, out + (size_t)r0 * 128, logdet + r0);
  }
}

// Round 9
// 741.254 us; speedup vs baseline: 1.0838x; 1.0790x over previous
//
#include <hip/hip_runtime.h>
#include <stdint.h>

// ---------- types ----------
typedef __attribute__((ext_vector_type(8))) __bf16 bf16x8;
typedef __attribute__((ext_vector_type(4))) float f32x4;

#define MIN_WF 0.001f
#define MIN_HF 0.001f
#define MIN_DF 0.001f
#define BN_INV 0.99999500003749977f /* 1/sqrt(1+1e-5) */

// async global->LDS, 16B per lane; LDS dest = wave-uniform base + lane*16
#define GLL(g, l)                                                              \
  __builtin_amdgcn_global_load_lds(                                            \
      (const __attribute__((address_space(1))) void*)(g),                      \
      (__attribute__((address_space(3))) void*)(l), 16, 0, 0)

__device__ __forceinline__ unsigned short f2bf(float f) {
  union { float f; unsigned int u; } v; v.f = f;
  unsigned int r = v.u + 0x7FFFu + ((v.u >> 16) & 1u);
  return (unsigned short)(r >> 16);
}

// ---------- cast/select even columns of x -> bf16 (Bc x 64) ----------
__global__ void cast_x_kernel(const float* __restrict__ x, unsigned short* __restrict__ xt) {
  int gid = blockIdx.x * blockDim.x + threadIdx.x; // 0 .. Bc*64
  int b = gid >> 6, i = gid & 63;
  xt[gid] = f2bf(x[(size_t)b * 128 + 2 * i]);
}

// ---------- transpose + cast: W (KxN f32, row-major) -> Wt (NxK bf16) ----------
__global__ void transpose_cast_kernel(const float* __restrict__ W, unsigned short* __restrict__ Wt,
                                      int K, int N) {
  __shared__ float tile[32][33];
  int tx = threadIdx.x & 31, ty = threadIdx.x >> 5; // 256 threads: ty 0..7
  int n0 = blockIdx.x * 32, k0 = blockIdx.y * 32;
#pragma unroll
  for (int i = 0; i < 32; i += 8)
    tile[ty + i][tx] = W[(size_t)(k0 + ty + i) * N + n0 + tx];
  __syncthreads();
#pragma unroll
  for (int i = 0; i < 32; i += 8)
    Wt[(size_t)(n0 + ty + i) * K + k0 + tx] = f2bf(tile[tx][ty + i]);
}

// ---------- GEMM: C[M,N] = epi(A[M,K] @ Bt[N,K]^T) ----------
// m97 staging, K=64/barrier via two BK=32 planes, XOR-swizzled LDS banks,
// XCD-aware 2D block swizzle: XCD = id%8 owns a contiguous M-band; within an
// XCD, 4x4 tile groups keep the L2 working set (~4 A-strips + 4 B-strips
// = ~4 MB) inside one XCD-L2, so strips are fetched once per XCD at most.
// EPI==1: v=relu(v+bias); v=gamma*BN_INV*v+beta; store bf16.  EPI==0: v=v+bias; store f32.
template <int EPI>
__global__ __launch_bounds__(256) void gemm_bt_kernel(
    const unsigned short* __restrict__ A, const unsigned short* __restrict__ Bt,
    const float* __restrict__ bias, const float* __restrict__ gamma,
    const float* __restrict__ beta, void* __restrict__ Cout,
    int M, int N, int K) {
  constexpr int BM = 128, BN = 128, BK = 32;
  __shared__ __align__(16) unsigned short As[2][BM * BK]; // 16 KB
  __shared__ __align__(16) unsigned short Bs[2][BN * BK]; // 16 KB
  int tid = threadIdx.x;
  int lane = tid & 63;
  int wave = tid >> 6;
  int wm = (wave & 1) * 64;
  int wn = (wave >> 1) * 64;
  int ml = lane & 15;
  int kq = lane >> 4;

  // ---- XCD-aware block swizzle (1D grid) ----
  int L = blockIdx.x;
  int Nt = N >> 7;
  int Mt = M >> 7;
  int mt, nt;
  int Mloc = Mt >> 3; // M-strips per XCD
  if (((Mt & 7) == 0) && ((Mloc & 3) == 0) && ((Nt & 3) == 0)) {
    int xcd = L & 7;
    int i = L >> 3;          // index within this XCD's block list
    int Ng = Nt >> 2;        // 4-wide N groups
    int ln = i & 3;
    int lm = (i >> 2) & 3;
    int g = i >> 4;          // gm * Ng + gn
    int gn = g % Ng;
    int gm = g / Ng;
    mt = xcd * Mloc + gm * 4 + lm;
    nt = gn * 4 + ln;
  } else {
    mt = L / Nt;
    nt = L % Nt;
  }
  size_t bm = (size_t)mt * BM;
  size_t bn = (size_t)nt * BN;

  // staging: wave w stages rows [w*32, +32); lane covers row sr=lane>>2.
  // physical group cg=lane&3 holds logical group g=(cg - (sr>>1))&3.
  int sr = lane >> 2;
  int sc = ((((lane & 3) + 4) - ((lane >> 3) & 3)) & 3) * 8;
  const unsigned short* gA = A + (bm + wave * 32 + sr) * (size_t)K + sc;
  const unsigned short* gB = Bt + (bn + wave * 32 + sr) * (size_t)K + sc;
  unsigned short* lA0 = As[0] + wave * 32 * BK;
  unsigned short* lA1 = As[1] + wave * 32 * BK;
  unsigned short* lB0 = Bs[0] + wave * 32 * BK;
  unsigned short* lB1 = Bs[1] + wave * 32 * BK;

  // fragment-read swizzle: physical group p = (kq + ((ml>>1)&3)) & 3 (i/j-invariant).
  int kqs = ((kq + ((ml >> 1) & 3)) & 3) * 8;

  f32x4 zero = {0.f, 0.f, 0.f, 0.f};
  f32x4 acc[4][4];
#pragma unroll
  for (int i = 0; i < 4; i++)
#pragma unroll
    for (int j = 0; j < 4; j++) acc[i][j] = zero;

  for (int kb = 0; kb < K; kb += 64) {
    GLL(gA + kb, lA0);
    GLL(gA + kb + (size_t)16 * K, lA0 + 16 * BK);
    GLL(gA + kb + 32, lA1);
    GLL(gA + kb + 32 + (size_t)16 * K, lA1 + 16 * BK);
    GLL(gB + kb, lB0);
    GLL(gB + kb + (size_t)16 * K, lB0 + 16 * BK);
    GLL(gB + kb + 32, lB1);
    GLL(gB + kb + 32 + (size_t)16 * K, lB1 + 16 * BK);
    __syncthreads(); // vmcnt(0) drain: LDS-DMA complete

#pragma unroll
    for (int p = 0; p < 2; p++) {
      bf16x8 af[4], bfr[4];
#pragma unroll
      for (int i = 0; i < 4; i++)
        af[i] = *(const bf16x8*)(&As[p][(wm + i * 16 + ml) * BK + kqs]);
#pragma unroll
      for (int j = 0; j < 4; j++)
        bfr[j] = *(const bf16x8*)(&Bs[p][(wn + j * 16 + ml) * BK + kqs]);
#pragma unroll
      for (int i = 0; i < 4; i++)
#pragma unroll
        for (int j = 0; j < 4; j++)
          acc[i][j] = __builtin_amdgcn_mfma_f32_16x16x32_bf16(af[i], bfr[j], acc[i][j], 0, 0, 0);
    }
    __syncthreads();
  }

  // epilogue. D mapping: col = lane&15, row = (lane>>4)*4 + r
#pragma unroll
  for (int i = 0; i < 4; i++) {
#pragma unroll
    for (int j = 0; j < 4; j++) {
      size_t col = bn + wn + j * 16 + ml;
      float bv = bias[col];
      float gv = (EPI == 1) ? gamma[col] * BN_INV : 0.f;
      float bev = (EPI == 1) ? beta[col] : 0.f;
#pragma unroll
      for (int r = 0; r < 4; r++) {
        size_t row = bm + wm + i * 16 + kq * 4 + r;
        float v = acc[i][j][r] + bv;
        if (EPI == 1) {
          v = fmaxf(v, 0.f);
          v = gv * v + bev;
          ((unsigned short*)Cout)[row * (size_t)N + col] = f2bf(v);
        } else {
          ((float*)Cout)[row * (size_t)N + col] = v;
        }
      }
    }
  }
}

// ---------- RQ spline + output assembly + log_det ----------
__global__ void spline_kernel(const float* __restrict__ x, const float* __restrict__ params,
                              float* __restrict__ out, float* __restrict__ logdet) {
  int gid = blockIdx.x * blockDim.x + threadIdx.x; // 0 .. Bc*64
  int b = gid >> 6;
  int i = gid & 63;

  const float4* p = (const float4*)(params + (size_t)gid * 24);
  float4 q0 = p[0], q1 = p[1], q2 = p[2], q3 = p[3], q4 = p[4], q5 = p[5];
  float w[8] = {q0.x, q0.y, q0.z, q0.w, q1.x, q1.y, q1.z, q1.w};
  float hh[8] = {q2.x, q2.y, q2.z, q2.w, q3.x, q3.y, q3.z, q3.w};
  float dv[8] = {q4.x, q4.y, q4.z, q4.w, q5.x, q5.y, q5.z, q5.w};

  float mx = w[0];
#pragma unroll
  for (int k = 1; k < 8; k++) mx = fmaxf(mx, w[k]);
  float s = 0.f;
#pragma unroll
  for (int k = 0; k < 8; k++) { w[k] = expf(w[k] - mx); s += w[k]; }
  float sc = (1.f - 8.f * MIN_WF) / s;
  float cw[9];
  cw[0] = 0.f;
#pragma unroll
  for (int k = 0; k < 8; k++) cw[k + 1] = cw[k] + (MIN_WF + sc * w[k]);

  float mh = hh[0];
#pragma unroll
  for (int k = 1; k < 8; k++) mh = fmaxf(mh, hh[k]);
  float sh = 0.f;
#pragma unroll
  for (int k = 0; k < 8; k++) { hh[k] = expf(hh[k] - mh); sh += hh[k]; }
  float sch = (1.f - 8.f * MIN_HF) / sh;
  float ch[9];
  ch[0] = 0.f;
#pragma unroll
  for (int k = 0; k < 8; k++) ch[k + 1] = ch[k] + (MIN_HF + sch * hh[k]);

  float dk[9];
#pragma unroll
  for (int k = 0; k < 8; k++)
    dk[k] = MIN_DF + (fmaxf(dv[k], 0.f) + log1pf(expf(-fabsf(dv[k]))));
  dk[8] = MIN_DF;

  float xv = x[(size_t)b * 128 + 2 * i + 1]; // identity (odd) column

  int bi = 0;
#pragma unroll
  for (int k = 0; k < 8; k++) bi += (xv > cw[k]) ? 1 : 0;
  bi = (bi > 7) ? 7 : bi;

  float xl = 0.f, xr = 0.f, yl = 0.f, yr = 0.f, dl = 0.f, dr = 0.f;
#pragma unroll
  for (int k = 0; k < 8; k++) {
    if (k == bi) {
      xl = cw[k]; xr = cw[k + 1];
      yl = ch[k]; yr = ch[k + 1];
      dl = dk[k]; dr = dk[k + 1];
    }
  }

  float bw = xr - xl, bh = yr - yl;
  float t = (xv - xl) / bw;
  t = fminf(fmaxf(t, 0.f), 1.f);
  float num = bh * (dl * t * t + 2.f * t * (1.f - t));
  float den = dl + (dr - dl) * t;
  float o = yl + num / den;
  float ld = logf(bh) + 2.f * logf(2.f * t * (1.f - t) * dr + dl) - logf(den);

  float xe = x[(size_t)b * 128 + 2 * i]; // transform (even) column passthrough
  ((float2*)out)[(size_t)b * 64 + i] = make_float2(xe, o);

#pragma unroll
  for (int off = 32; off > 0; off >>= 1) ld += __shfl_xor(ld, off, 64);
  if ((threadIdx.x & 63) == 0) logdet[b] = ld;
}

// ---------- launch ----------
extern "C" void kernel_launch(void* const* d_in, const int* in_sizes, int n_in,
                              void* d_out, int out_size, void* d_ws, size_t ws_size,
                              hipStream_t stream) {
  const float* x   = (const float*)d_in[0];
  const float* W1  = (const float*)d_in[1];
  const float* b1  = (const float*)d_in[2];
  const float* g1  = (const float*)d_in[3];
  const float* be1 = (const float*)d_in[4];
  const float* W2  = (const float*)d_in[5];
  const float* b2  = (const float*)d_in[6];
  const float* g2  = (const float*)d_in[7];
  const float* be2 = (const float*)d_in[8];
  const float* W3  = (const float*)d_in[9];
  const float* b3  = (const float*)d_in[10];

  const int B = 32768, H = 2048, DOUT = 1536;

  // ---- workspace layout (chunked) ----
  // persistent weights: W1t 262,144 + W2t 8,388,608 + W3t 6,291,456 = 14,942,208 B
  // per chunk of Bc rows: xt 128*Bc + h2 4096*Bc + max(h1 4096*Bc, params 6144*Bc)
  const size_t WEIGHTS = 14942208;
  int Bc = 1024;
  {
    const int cand[5] = {32768, 16384, 8192, 4096, 2048};
    for (int c = 0; c < 5; c++) {
      size_t need = WEIGHTS + (size_t)10368 * cand[c];
      if (need <= ws_size) { Bc = cand[c]; break; }
    }
  }
  char* ws = (char*)d_ws;
  unsigned short* W1t = (unsigned short*)(ws + 0);
  unsigned short* W2t = (unsigned short*)(ws + 262144);
  unsigned short* W3t = (unsigned short*)(ws + 8650752);
  unsigned short* xt  = (unsigned short*)(ws + WEIGHTS);
  unsigned short* h2  = (unsigned short*)(ws + WEIGHTS + (size_t)128 * Bc);
  char*           uni = ws + WEIGHTS + (size_t)(128 + 4096) * Bc;
  unsigned short* h1  = (unsigned short*)uni;
  float*      params  = (float*)uni; // aliases h1 (dead when GEMM3 writes)

  float* out = (float*)d_out;
  float* logdet = out + (size_t)B * 128;

  transpose_cast_kernel<<<dim3(64, 2), dim3(256), 0, stream>>>(W1, W1t, 64, H);
  transpose_cast_kernel<<<dim3(64, 64), dim3(256), 0, stream>>>(W2, W2t, H, H);
  transpose_cast_kernel<<<dim3(48, 64), dim3(256), 0, stream>>>(W3, W3t, H, DOUT);

  // GEMM grids are 1D: Mt*Nt blocks; the kernel derives (m,n) via XCD swizzle.
  for (int r0 = 0; r0 < B; r0 += Bc) {
    cast_x_kernel<<<dim3(Bc / 4), dim3(256), 0, stream>>>(x + (size_t)r0 * 128, xt);
    gemm_bt_kernel<1><<<dim3((Bc / 128) * 16), dim3(256), 0, stream>>>(
        xt, W1t, b1, g1, be1, (void*)h1, Bc, H, 64);
    gemm_bt_kernel<1><<<dim3((Bc / 128) * 16), dim3(256), 0, stream>>>(
        h1, W2t, b2, g2, be2, (void*)h2, Bc, H, H);
    gemm_bt_kernel<0><<<dim3((Bc / 128) * 12), dim3(256), 0, stream>>>(
        h2, W3t, b3, b3, b3, (void*)params, Bc, DOUT, H);
    spline_kernel<<<dim3(Bc / 4), dim3(256), 0, stream>>>(
        x + (size_t)r0 * 128, params, out + (size_t)r0 * 128, logdet + r0);
  }
}